// Round 1
// 381.278 us; speedup vs baseline: 1.1497x; 1.1497x over previous
//
#include <hip/hip_runtime.h>
#include <math.h>

#define NN 8
#define TT 8
#define CC 128
#define HH 64
#define WW 64
#define HW 4096

typedef unsigned int u32;
typedef unsigned short u16;
typedef __attribute__((ext_vector_type(8))) short short8;
typedef __attribute__((ext_vector_type(4))) float floatx4;

__device__ __forceinline__ u16 f2bf(float f){
    u32 u = __float_as_uint(f);
    u32 r = (u + 0x7fffu + ((u >> 16) & 1u)) >> 16;   // RNE
    return (u16)r;
}
__device__ __forceinline__ float bf2f(u16 h){
    return __uint_as_float(((u32)h) << 16);
}

// ---------------- K1: M[n,t,c] = mean_hw(x) + max_hw(x) -------------------
__global__ __launch_bounds__(256) void k1_M(const float* __restrict__ x, float* __restrict__ M){
    int plane = blockIdx.x * 4 + (threadIdx.x >> 6);
    int lane  = threadIdx.x & 63;
    const float* p = x + (size_t)plane * HW;
    float s = 0.f, mx = -INFINITY;
    #pragma unroll
    for (int it = 0; it < 16; ++it){
        float4 v = *(const float4*)(p + it*256 + lane*4);
        s += v.x + v.y + v.z + v.w;
        mx = fmaxf(mx, fmaxf(fmaxf(v.x, v.y), fmaxf(v.z, v.w)));
    }
    #pragma unroll
    for (int off = 32; off > 0; off >>= 1){
        s += __shfl_xor(s, off, 64);
        mx = fmaxf(mx, __shfl_xor(mx, off, 64));
    }
    if (lane == 0) M[plane] = s * (1.0f/(float)HW) + mx;
}

// ---------------- K2: imp[t,c] = XOR of unioned top-k masks ---------------
__global__ __launch_bounds__(128) void k2_imp(const float* __restrict__ M, float* __restrict__ imp){
    int t = blockIdx.x;       // 0..7
    int c = threadIdx.x;      // 0..127
    __shared__ float Ms[NN*CC];
    for (int n = 0; n < NN; ++n)
        Ms[n*CC + c] = M[(n*TT + t)*CC + c];
    __syncthreads();
    bool sel_ch = false;
    for (int n = 0; n < NN; ++n){
        float mv = Ms[n*CC + c];
        int rank = 0;
        for (int c2 = 0; c2 < CC; ++c2){
            float v2 = Ms[n*CC + c2];
            rank += (v2 > mv) || (v2 == mv && c2 < c);
        }
        sel_ch = sel_ch || (rank < 64);   // kc = 64
    }
    bool sel_tm = false;
    for (int n = 0; n < NN; ++n){
        float mv = M[(n*TT + t)*CC + c];
        int rank = 0;
        for (int t2 = 0; t2 < TT; ++t2){
            float v2 = M[(n*TT + t2)*CC + c];
            rank += (v2 > mv) || (v2 == mv && t2 < t);
        }
        sel_tm = sel_tm || (rank < 4);    // kt = 4
    }
    imp[t*CC + c] = (sel_ch != sel_tm) ? 1.0f : 0.0f;
}

// ---------------- K3a: channel stats (bf16 out) ---------------------------
__global__ __launch_bounds__(512) void k3a_stats(const float* __restrict__ x,
        const float* __restrict__ imp, u16* __restrict__ st){
    int nt = blockIdx.x; int t = nt & 7;
    int px = blockIdx.y * 512 + threadIdx.x;
    const float* xp = x + (size_t)nt * CC * HW + px;
    float sa = 0.f, sb = 0.f, ma = -INFINITY, mb = -INFINITY;
    for (int c = 0; c < CC; ++c){
        float ip = imp[t*CC + c];
        float v = xp[c*HW];
        float a = ip*v, b = v - a;
        sa += a; sb += b;
        ma = fmaxf(ma, a); mb = fmaxf(mb, b);
    }
    st[(nt*4+0)*HW + px] = f2bf(sa * (1.f/64.f));   // mean/128/0.5
    st[(nt*4+1)*HW + px] = f2bf(ma);
    st[(nt*4+2)*HW + px] = f2bf(sb * (1.f/64.f));
    st[(nt*4+3)*HW + px] = f2bf(mb);
}

// ---------------- K3b: 3x3 conv + sigmoid -> maps -------------------------
__global__ __launch_bounds__(256) void k3b_maps(const u16* __restrict__ st,
        const float* __restrict__ w1, const float* __restrict__ w2,
        float* __restrict__ maps){
    int nt = blockIdx.x;
    int y0 = blockIdx.y * 16;
    __shared__ float S[4*18*66];
    int tid = threadIdx.x;
    for (int idx = tid; idx < 4*18*66; idx += 256){
        int s  = idx / 1188;
        int r  = (idx % 1188) / 66;
        int xx = idx % 66;
        int gy = y0 - 1 + r, gx = xx - 1;
        float v = 0.f;
        if ((u32)gy < HH && (u32)gx < WW)
            v = bf2f(st[(nt*4 + s)*HW + gy*WW + gx]);
        S[idx] = v;
    }
    __syncthreads();
    float wa[18], wb[18];
    #pragma unroll
    for (int i = 0; i < 18; ++i){ wa[i] = w1[i]; wb[i] = w2[i]; }
    for (int k = 0; k < 4; ++k){
        int p = k*256 + tid;
        int y = p >> 6, xx = p & 63;
        float zi = 0.f, zs = 0.f;
        #pragma unroll
        for (int dy = 0; dy < 3; ++dy)
            #pragma unroll
            for (int dx = 0; dx < 3; ++dx){
                int sp = (y+dy)*66 + xx + dx;
                zi += wa[dy*3+dx] * S[sp] + wa[9+dy*3+dx] * S[1188 + sp];
                zs += wb[dy*3+dx] * S[2376 + sp] + wb[9+dy*3+dx] * S[3564 + sp];
            }
        maps[(nt*2+0)*HW + y0*WW + p] = 1.0f / (1.0f + expf(-zi));
        maps[(nt*2+1)*HW + y0*WW + p] = 1.0f / (1.0f + expf(-zs));
    }
}

// ---------------- K4: xs[n][c][p][t] = bf16( x * (imp? im_map : sub_map) ) -
__global__ __launch_bounds__(256) void k4_xs(const float* __restrict__ x,
        const float* __restrict__ impf, const float* __restrict__ maps,
        u16* __restrict__ xs){
    int c = blockIdx.x;      // 0..127
    int n = blockIdx.y;      // 0..7
    int tid = threadIdx.x;
    const float* mp[TT];
    #pragma unroll
    for (int t = 0; t < TT; ++t){
        float v = impf[t*CC + c];
        mp[t] = maps + ((size_t)((n*TT + t)*2) + (v > 0.f ? 0 : 1)) * HW;
    }
    const float* xb = x + ((size_t)(n*TT)*CC + c) * HW;
    u16* xr = xs + ((size_t)n*CC + c) * HW * 8;
    for (int it = 0; it < 16; ++it){
        int p = it*256 + tid;
        union { u16 h[8]; uint4 v4; } r;
        #pragma unroll
        for (int t = 0; t < TT; ++t){
            float xv = xb[(size_t)t*CC*HW + p];
            r.h[t] = f2bf(xv * mp[t][p]);
        }
        *(uint4*)(xr + (size_t)p*8) = r.v4;
    }
}

// ---------------- KW: folded A-fragments per output channel ---------------
// Fold im/sub selection into weights: since exactly one of htsa[t], htsa[t+8]
// is nonzero at input channel c (and equals xs_t), the 16-ch sum collapses to
// 8 products with weight w[o][ imp(t,c) ? t : t+8 ]. K=32 = 8t x 4 taps.
// fw[c_out][stp 0..6][lane 0..63] = 16-B A-fragment record:
//   m = lane&15 (out ch, 8..15 zero), q = lane>>4, tap = 4*stp+q, j = t.
__global__ __launch_bounds__(64) void kW_frag(const float* __restrict__ wlast,
        const float* __restrict__ impf, u16* __restrict__ fw){
    int c_out = blockIdx.x;     // 0..127
    int stp   = blockIdx.y;     // 0..6
    int lane  = threadIdx.x;    // 0..63
    int m = lane & 15, q = lane >> 4;
    int tap = 4*stp + q;
    int dc = tap / 9;
    int c_in = c_out - 1 + dc;
    bool valid = (m < 8) && (tap < 27) && ((u32)c_in < CC);
    union { u16 h[8]; uint4 v; } pk;
    #pragma unroll
    for (int j = 0; j < 8; ++j){
        float wv = 0.f;
        if (valid){
            int idx = (impf[j*CC + c_in] > 0.f) ? j : j + 8;
            wv = wlast[(m*16 + idx)*27 + tap];
        }
        pk.h[j] = f2bf(wv);
    }
    *(uint4*)(fw + (((size_t)c_out*7 + stp)*64 + lane)*8) = pk.v;
}

// ---------------- K5: MFMA fused 3D conv (folded weights) -----------------
// mfma_f32_16x16x32_bf16: M=16 -> o (8 real), N=16 -> x pixels,
// K=32 -> 8 t-slots x 4 taps (7 steps cover 27 taps + 1 pad).
// LDS: single raw xs tile [4c][6y][66x], 16-B records -> conflict-free b128.
constexpr int offb16(int tap){
    return (((tap/9)*6 + ((tap/3)%3))*66 + (tap%3))*16;
}

__global__ __launch_bounds__(256, 6) void k5_fold(
        const u16* __restrict__ xs, const u16* __restrict__ fw,
        float* __restrict__ out){
    __shared__ __align__(16) u16 ft[1584*8];    // 25,344 B -> 6 blocks/CU
    int tid  = threadIdx.x;
    int lane = tid & 63;
    int w    = tid >> 6;
    int c0 = blockIdx.x * 2;
    int y0 = blockIdx.y * 4;
    int n  = blockIdx.z;
    int cl = w & 1;
    int c_out = c0 + cl;

    // A fragments straight from global (0.9 MB table, L2-hot)
    short8 afr[7];
    const u16* fwb = fw + ((size_t)c_out*7*64 + lane)*8;
    #pragma unroll
    for (int stp = 0; stp < 7; ++stp)
        afr[stp] = *(const short8*)(fwb + stp*512);

    // ---- stage raw feature tile (4c x 6y x 66x), no masks -----------------
    for (int idx = tid; idx < 1584; idx += 256){
        int cc  = idx / 396;
        int rm  = idx % 396;
        int yyl = rm / 66;
        int xx  = rm % 66;
        int gc = c0 - 1 + cc;
        int gy = y0 - 1 + yyl;
        int gx = xx - 1;
        uint4 v = make_uint4(0,0,0,0);
        if ((u32)gc < CC && (u32)gy < HH && (u32)gx < WW)
            v = *(const uint4*)(xs + (((size_t)n*CC + gc)*HW + gy*WW + gx)*8);
        *(uint4*)(ft + idx*8) = v;
    }
    __syncthreads();

    // ---- MFMA main --------------------------------------------------------
    int col = lane & 15;
    int q   = lane >> 4;             // which tap of the 4 in this K-step
    const char* fb = (const char*)ft;
    int offs[7];
    #pragma unroll
    for (int stp = 0; stp < 7; ++stp){
        int tap = 4*stp + q;
        if (tap >= 27) tap = 0;       // pad tap: safe addr, A is zero there
        offs[stp] = offb16(tap);
    }
    for (int yy = 0; yy < 2; ++yy){
        int yl = (w >> 1)*2 + yy;
        int rowb = ((cl*6 + yl)*66 + col)*16;
        #pragma unroll
        for (int xp = 0; xp < 2; ++xp){
            int b0off = rowb + xp*512;        // 32 px * 16 B
            int b1off = b0off + 256;          // +16 px
            floatx4 acc0 = {0.f,0.f,0.f,0.f};
            floatx4 acc1 = {0.f,0.f,0.f,0.f};
            #pragma unroll
            for (int stp = 0; stp < 7; ++stp){
                short8 b0 = *(const short8*)(fb + b0off + offs[stp]);
                short8 b1 = *(const short8*)(fb + b1off + offs[stp]);
                acc0 = __builtin_amdgcn_mfma_f32_16x16x32_bf16(afr[stp], b0, acc0, 0, 0, 0);
                acc1 = __builtin_amdgcn_mfma_f32_16x16x32_bf16(afr[stp], b1, acc1, 0, 0, 0);
            }
            // C/D: col = lane&15, row = (lane>>4)*4 + reg; rows 8..15 pad
            if (lane < 32){
                int y = y0 + yl;
                int xa = xp*32 + col;
                #pragma unroll
                for (int rg = 0; rg < 4; ++rg){
                    int o = (lane >> 4)*4 + rg;
                    size_t ob = (((size_t)(n*TT + o))*CC + c_out)*HW + y*WW;
                    out[ob + xa]      = acc0[rg];
                    out[ob + xa + 16] = acc1[rg];
                }
            }
        }
    }
}

// ---------------- K5 fallback (no workspace): original masked version ------
template<bool USE_XS>
__global__ __launch_bounds__(256) void k5_conv3d(
        const float* __restrict__ x, const u16* __restrict__ xs,
        const float* __restrict__ impf, const float* __restrict__ wlast,
        const float* __restrict__ maps, float* __restrict__ out){
    __shared__ __align__(16) u16 fim[1584*8];    // 25,344 B
    __shared__ __align__(16) u16 fsb[1584*8];    // 25,344 B
    __shared__ u32 maskw[CC*4];                  //  2,048 B
    int tid  = threadIdx.x;
    int lane = tid & 63;
    int w    = tid >> 6;
    int c0 = blockIdx.x * 2;
    int y0 = blockIdx.y * 4;
    int n  = blockIdx.z;

    for (int idx = tid; idx < CC*4; idx += 256){
        int c = idx >> 2, j = idx & 3;
        u32 m = (impf[(2*j)*CC + c]   > 0.f ? 0x0000FFFFu : 0u)
              | (impf[(2*j+1)*CC + c] > 0.f ? 0xFFFF0000u : 0u);
        maskw[idx] = m;
    }

    for (int idx = tid; idx < 896; idx += 256){
        int stp = idx >> 6;
        int l   = idx & 63;
        int m = l & 15, q = l >> 4;
        int i0 = (q & 1) * 8, s = q >> 1;
        int tap = 2*stp + s;
        bool valid = (m < 8) && (tap < 27);
        union { u16 h[8]; uint4 v; } pk;
        #pragma unroll
        for (int j = 0; j < 8; ++j){
            float wv = valid ? wlast[(m*16 + i0 + j)*27 + tap] : 0.f;
            pk.h[j] = f2bf(wv);
        }
        *(uint4*)(fim + idx*8) = pk.v;
    }
    __syncthreads();
    short8 afr[14];
    #pragma unroll
    for (int stp = 0; stp < 14; ++stp)
        afr[stp] = *(const short8*)(fim + (stp*64 + lane)*8);
    __syncthreads();

    for (int idx = tid; idx < 1584; idx += 256){
        int cc  = idx / 396;
        int rm  = idx % 396;
        int yyl = rm / 66;
        int xx  = rm % 66;
        int gc = c0 - 1 + cc;
        int gy = y0 - 1 + yyl;
        int gx = xx - 1;
        uint4 vim = make_uint4(0,0,0,0), vsb = make_uint4(0,0,0,0);
        if ((u32)gc < CC && (u32)gy < HH && (u32)gx < WW){
            int gp = gy*WW + gx;
            u32 al[4];
            if (USE_XS){
                uint4 v = *(const uint4*)(xs + (((size_t)n*CC + gc)*HW + gp)*8);
                al[0] = v.x; al[1] = v.y; al[2] = v.z; al[3] = v.w;
            } else {
                const float* xn  = x    + (((size_t)(n*TT))*CC + gc)*HW + gp;
                const float* mpn = maps + ((size_t)n*TT*2)*HW + gp;
                u16 hv[8];
                #pragma unroll
                for (int t = 0; t < TT; ++t){
                    float ip = impf[t*CC + gc];
                    float xv = xn[(size_t)t*CC*HW];
                    float mv = mpn[((size_t)t*2 + (ip > 0.f ? 0 : 1))*HW];
                    hv[t] = f2bf(xv * mv);
                }
                #pragma unroll
                for (int j = 0; j < 4; ++j)
                    al[j] = (u32)hv[2*j] | ((u32)hv[2*j+1] << 16);
            }
            u32 m0 = maskw[gc*4+0], m1 = maskw[gc*4+1];
            u32 m2 = maskw[gc*4+2], m3 = maskw[gc*4+3];
            vim.x = al[0] & m0; vim.y = al[1] & m1;
            vim.z = al[2] & m2; vim.w = al[3] & m3;
            vsb.x = al[0] ^ vim.x; vsb.y = al[1] ^ vim.y;
            vsb.z = al[2] ^ vim.z; vsb.w = al[3] ^ vim.w;
        }
        *(uint4*)(fim + idx*8) = vim;
        *(uint4*)(fsb + idx*8) = vsb;
    }
    __syncthreads();

    int col = lane & 15;
    int q   = (lane >> 4) & 1;
    int s   = lane >> 5;
    const char* fb = (const char*)(q ? fsb : fim);
    int offs[14];
    #pragma unroll
    for (int stp = 0; stp < 14; ++stp){
        int tap = 2*stp + s;
        if (tap >= 27) tap = 0;
        offs[stp] = offb16(tap);
    }
    int cl = w & 1;
    for (int yy = 0; yy < 2; ++yy){
        int yl = (w >> 1)*2 + yy;
        int rowb = ((cl*6 + yl)*66 + col)*16;
        #pragma unroll
        for (int xp = 0; xp < 2; ++xp){
            int b0off = rowb + xp*512;
            int b1off = b0off + 256;
            floatx4 acc0 = {0.f,0.f,0.f,0.f};
            floatx4 acc1 = {0.f,0.f,0.f,0.f};
            #pragma unroll
            for (int stp = 0; stp < 14; ++stp){
                short8 b0 = *(const short8*)(fb + b0off + offs[stp]);
                short8 b1 = *(const short8*)(fb + b1off + offs[stp]);
                acc0 = __builtin_amdgcn_mfma_f32_16x16x32_bf16(afr[stp], b0, acc0, 0, 0, 0);
                acc1 = __builtin_amdgcn_mfma_f32_16x16x32_bf16(afr[stp], b1, acc1, 0, 0, 0);
            }
            if (lane < 32){
                int c = c0 + cl, y = y0 + yl;
                int xa = xp*32 + col;
                #pragma unroll
                for (int rg = 0; rg < 4; ++rg){
                    int o = (lane >> 4)*4 + rg;
                    size_t ob = (((size_t)(n*TT + o))*CC + c)*HW + y*WW;
                    out[ob + xa]      = acc0[rg];
                    out[ob + xa + 16] = acc1[rg];
                }
            }
        }
    }
}

extern "C" void kernel_launch(void* const* d_in, const int* in_sizes, int n_in,
                              void* d_out, int out_size, void* d_ws, size_t ws_size,
                              hipStream_t stream){
    const float* x     = (const float*)d_in[0];   // (8,8,128,64,64) fp32
    const float* w1    = (const float*)d_in[1];   // (1,2,3,3)
    const float* w2    = (const float*)d_in[2];   // (1,2,3,3)
    const float* wlast = (const float*)d_in[3];   // (8,16,3,3,3)
    float* out = (float*)d_out;

    float* ws   = (float*)d_ws;
    float* M    = ws;                           // 8,192 f32
    float* imp  = ws + 8192;                    // 1,024 f32
    float* maps = ws + 9216;                    // 524,288 f32
    u16*   st   = (u16*)(ws + 9216 + 524288);   // 1,048,576 u16 (2 MB)
    u16*   xs   = (u16*)(ws + 9216 + 524288 + 524288);  // 67,108,864 B
    u16*   fw   = st;   // folded A-fragments (917,504 B) alias st (dead after k3b)
    const size_t WS_NEED = (size_t)(9216 + 524288 + 524288) * 4 + (size_t)NN*TT*CC*HW*2;

    k1_M      <<<dim3(NN*TT*CC/4), dim3(256), 0, stream>>>(x, M);
    k2_imp    <<<dim3(TT),         dim3(128), 0, stream>>>(M, imp);
    k3a_stats <<<dim3(NN*TT, 8),   dim3(512), 0, stream>>>(x, imp, st);
    k3b_maps  <<<dim3(NN*TT, 4),   dim3(256), 0, stream>>>(st, w1, w2, maps);
    if (ws_size >= WS_NEED){
        kW_frag <<<dim3(CC, 7), dim3(64),  0, stream>>>(wlast, imp, fw);
        k4_xs   <<<dim3(CC, NN), dim3(256), 0, stream>>>(x, imp, maps, xs);
        k5_fold <<<dim3(CC/2, HH/4, NN), dim3(256), 0, stream>>>(xs, fw, out);
    } else {
        k5_conv3d<false> <<<dim3(CC/2, HH/4, NN), dim3(256), 0, stream>>>(x, xs, imp, wlast, maps, out);
    }
}

// Round 2
// 349.234 us; speedup vs baseline: 1.2552x; 1.0918x over previous
//
#include <hip/hip_runtime.h>
#include <math.h>

#define NN 8
#define TT 8
#define CC 128
#define HH 64
#define WW 64
#define HW 4096

typedef unsigned int u32;
typedef unsigned short u16;
typedef __attribute__((ext_vector_type(8))) short short8;
typedef __attribute__((ext_vector_type(4))) float floatx4;

__device__ __forceinline__ u16 f2bf(float f){
    u32 u = __float_as_uint(f);
    u32 r = (u + 0x7fffu + ((u >> 16) & 1u)) >> 16;   // RNE
    return (u16)r;
}
__device__ __forceinline__ float bf2f(u16 h){
    return __uint_as_float(((u32)h) << 16);
}

// ---------------- K1: M[n,t,c] = mean_hw(x) + max_hw(x) -------------------
__global__ __launch_bounds__(256) void k1_M(const float* __restrict__ x, float* __restrict__ M){
    int plane = blockIdx.x * 4 + (threadIdx.x >> 6);
    int lane  = threadIdx.x & 63;
    const float* p = x + (size_t)plane * HW;
    float s = 0.f, mx = -INFINITY;
    #pragma unroll
    for (int it = 0; it < 16; ++it){
        float4 v = *(const float4*)(p + it*256 + lane*4);
        s += v.x + v.y + v.z + v.w;
        mx = fmaxf(mx, fmaxf(fmaxf(v.x, v.y), fmaxf(v.z, v.w)));
    }
    #pragma unroll
    for (int off = 32; off > 0; off >>= 1){
        s += __shfl_xor(s, off, 64);
        mx = fmaxf(mx, __shfl_xor(mx, off, 64));
    }
    if (lane == 0) M[plane] = s * (1.0f/(float)HW) + mx;
}

// ---------------- K2: imp[t,c] = XOR of unioned top-k masks ---------------
__global__ __launch_bounds__(128) void k2_imp(const float* __restrict__ M, float* __restrict__ imp){
    int t = blockIdx.x;       // 0..7
    int c = threadIdx.x;      // 0..127
    __shared__ float Ms[NN*CC];
    for (int n = 0; n < NN; ++n)
        Ms[n*CC + c] = M[(n*TT + t)*CC + c];
    __syncthreads();
    bool sel_ch = false;
    for (int n = 0; n < NN; ++n){
        float mv = Ms[n*CC + c];
        int rank = 0;
        for (int c2 = 0; c2 < CC; ++c2){
            float v2 = Ms[n*CC + c2];
            rank += (v2 > mv) || (v2 == mv && c2 < c);
        }
        sel_ch = sel_ch || (rank < 64);   // kc = 64
    }
    bool sel_tm = false;
    for (int n = 0; n < NN; ++n){
        float mv = M[(n*TT + t)*CC + c];
        int rank = 0;
        for (int t2 = 0; t2 < TT; ++t2){
            float v2 = M[(n*TT + t2)*CC + c];
            rank += (v2 > mv) || (v2 == mv && t2 < t);
        }
        sel_tm = sel_tm || (rank < 4);    // kt = 4
    }
    imp[t*CC + c] = (sel_ch != sel_tm) ? 1.0f : 0.0f;
}

// ---------------- K3a: channel stats (bf16 out), float4 px ----------------
__global__ __launch_bounds__(512) void k3a_stats(const float* __restrict__ x,
        const float* __restrict__ imp, u16* __restrict__ st){
    int nt = blockIdx.x; int t = nt & 7;
    int px = (blockIdx.y * 512 + threadIdx.x) * 4;
    __shared__ float ipr[CC];
    if (threadIdx.x < CC) ipr[threadIdx.x] = imp[t*CC + threadIdx.x];
    __syncthreads();
    const float* xp = x + (size_t)nt * CC * HW + px;
    float sa[4] = {0,0,0,0}, sb[4] = {0,0,0,0};
    float ma[4] = {-INFINITY,-INFINITY,-INFINITY,-INFINITY};
    float mb[4] = {-INFINITY,-INFINITY,-INFINITY,-INFINITY};
    for (int c = 0; c < CC; ++c){
        float ip = ipr[c];
        float4 v = *(const float4*)(xp + (size_t)c*HW);
        float vv[4] = {v.x, v.y, v.z, v.w};
        #pragma unroll
        for (int j = 0; j < 4; ++j){
            float a = ip*vv[j], b = vv[j] - a;
            sa[j] += a; sb[j] += b;
            ma[j] = fmaxf(ma[j], a); mb[j] = fmaxf(mb[j], b);
        }
    }
    union { u16 h[4]; uint2 v2; } o;
    #pragma unroll
    for (int j = 0; j < 4; ++j) o.h[j] = f2bf(sa[j] * (1.f/64.f));
    *(uint2*)(st + (nt*4+0)*HW + px) = o.v2;
    #pragma unroll
    for (int j = 0; j < 4; ++j) o.h[j] = f2bf(ma[j]);
    *(uint2*)(st + (nt*4+1)*HW + px) = o.v2;
    #pragma unroll
    for (int j = 0; j < 4; ++j) o.h[j] = f2bf(sb[j] * (1.f/64.f));
    *(uint2*)(st + (nt*4+2)*HW + px) = o.v2;
    #pragma unroll
    for (int j = 0; j < 4; ++j) o.h[j] = f2bf(mb[j]);
    *(uint2*)(st + (nt*4+3)*HW + px) = o.v2;
}

// ---------------- K3b: 3x3 conv + sigmoid -> maps -------------------------
__global__ __launch_bounds__(256) void k3b_maps(const u16* __restrict__ st,
        const float* __restrict__ w1, const float* __restrict__ w2,
        float* __restrict__ maps){
    int nt = blockIdx.x;
    int y0 = blockIdx.y * 16;
    __shared__ float S[4*18*66];
    int tid = threadIdx.x;
    for (int idx = tid; idx < 4*18*66; idx += 256){
        int s  = idx / 1188;
        int r  = (idx % 1188) / 66;
        int xx = idx % 66;
        int gy = y0 - 1 + r, gx = xx - 1;
        float v = 0.f;
        if ((u32)gy < HH && (u32)gx < WW)
            v = bf2f(st[(nt*4 + s)*HW + gy*WW + gx]);
        S[idx] = v;
    }
    __syncthreads();
    float wa[18], wb[18];
    #pragma unroll
    for (int i = 0; i < 18; ++i){ wa[i] = w1[i]; wb[i] = w2[i]; }
    for (int k = 0; k < 4; ++k){
        int p = k*256 + tid;
        int y = p >> 6, xx = p & 63;
        float zi = 0.f, zs = 0.f;
        #pragma unroll
        for (int dy = 0; dy < 3; ++dy)
            #pragma unroll
            for (int dx = 0; dx < 3; ++dx){
                int sp = (y+dy)*66 + xx + dx;
                zi += wa[dy*3+dx] * S[sp] + wa[9+dy*3+dx] * S[1188 + sp];
                zs += wb[dy*3+dx] * S[2376 + sp] + wb[9+dy*3+dx] * S[3564 + sp];
            }
        maps[(nt*2+0)*HW + y0*WW + p] = 1.0f / (1.0f + expf(-zi));
        maps[(nt*2+1)*HW + y0*WW + p] = 1.0f / (1.0f + expf(-zs));
    }
}

// ---------------- KW: folded A-fragments per output channel ---------------
// Fold im/sub selection into weights: since exactly one of htsa[t], htsa[t+8]
// is nonzero at input channel c (and equals xs_t), the 16-ch sum collapses to
// 8 products with weight w[o][ imp(t,c) ? t : t+8 ]. K=32 = 8t x 4 taps.
__global__ __launch_bounds__(64) void kW_frag(const float* __restrict__ wlast,
        const float* __restrict__ impf, u16* __restrict__ fw){
    int c_out = blockIdx.x;     // 0..127
    int stp   = blockIdx.y;     // 0..6
    int lane  = threadIdx.x;    // 0..63
    int m = lane & 15, q = lane >> 4;
    int tap = 4*stp + q;
    int dc = tap / 9;
    int c_in = c_out - 1 + dc;
    bool valid = (m < 8) && (tap < 27) && ((u32)c_in < CC);
    union { u16 h[8]; uint4 v; } pk;
    #pragma unroll
    for (int j = 0; j < 8; ++j){
        float wv = 0.f;
        if (valid){
            int idx = (impf[j*CC + c_in] > 0.f) ? j : j + 8;
            wv = wlast[(m*16 + idx)*27 + tap];
        }
        pk.h[j] = f2bf(wv);
    }
    *(uint4*)(fw + (((size_t)c_out*7 + stp)*64 + lane)*8) = pk.v;
}

// ---------------- K5: MFMA fused 3D conv, staging direct from x -----------
// mfma_f32_16x16x32_bf16: M=16 -> o (8 real), N=16 -> x pixels,
// K=32 -> 8 t-slots x 4 taps (7 steps cover 27 taps + 1 pad).
// Staging converts x*map to bf16 inline (k4 eliminated): 8 x-loads +
// 8 map-loads (25 KB/block map region -> L1-hot) per 16-B record.
constexpr int offb16(int tap){
    return (((tap/9)*6 + ((tap/3)%3))*66 + (tap%3))*16;
}

__global__ __launch_bounds__(256, 6) void k5_fuse(
        const float* __restrict__ x, const float* __restrict__ impf,
        const float* __restrict__ maps, const u16* __restrict__ fw,
        float* __restrict__ out){
    __shared__ __align__(16) u16 ft[1584*8];    // 25,344 B -> 6 blocks/CU
    __shared__ u32 mofs[4][8];                  // map plane offset per (cc,t)
    int tid  = threadIdx.x;
    int lane = tid & 63;
    int w    = tid >> 6;
    int c0 = blockIdx.x * 2;
    int y0 = blockIdx.y * 4;
    int n  = blockIdx.z;
    int cl = w & 1;
    int c_out = c0 + cl;

    if (tid < 32){
        int cc = tid >> 3, t = tid & 7;
        int gc = c0 - 1 + cc;
        float ip = ((u32)gc < CC) ? impf[t*CC + gc] : 0.f;
        mofs[cc][t] = (u32)(((n*TT + t)*2 + (ip > 0.f ? 0 : 1)) * HW);
    }

    // A fragments straight from global (0.9 MB table, L2-hot)
    short8 afr[7];
    const u16* fwb = fw + ((size_t)c_out*7*64 + lane)*8;
    #pragma unroll
    for (int stp = 0; stp < 7; ++stp)
        afr[stp] = *(const short8*)(fwb + stp*512);
    __syncthreads();

    // ---- stage feature tile (4c x 6y x 66x) directly from x ---------------
    for (int idx = tid; idx < 1584; idx += 256){
        int cc  = idx / 396;
        int rm  = idx % 396;
        int yyl = rm / 66;
        int xx  = rm % 66;
        int gc = c0 - 1 + cc;
        int gy = y0 - 1 + yyl;
        int gx = xx - 1;
        uint4 v = make_uint4(0,0,0,0);
        if ((u32)gc < CC && (u32)gy < HH && (u32)gx < WW){
            int gp = gy*WW + gx;
            const float* xn = x + ((size_t)(n*TT)*CC + gc)*HW + gp;
            const float* mb = maps + gp;
            u16 hv[8];
            #pragma unroll
            for (int t = 0; t < TT; ++t){
                float xv = xn[(size_t)t*CC*HW];
                float mv = mb[mofs[cc][t]];
                hv[t] = f2bf(xv * mv);
            }
            v.x = (u32)hv[0] | ((u32)hv[1] << 16);
            v.y = (u32)hv[2] | ((u32)hv[3] << 16);
            v.z = (u32)hv[4] | ((u32)hv[5] << 16);
            v.w = (u32)hv[6] | ((u32)hv[7] << 16);
        }
        *(uint4*)(ft + idx*8) = v;
    }
    __syncthreads();

    // ---- MFMA main --------------------------------------------------------
    int col = lane & 15;
    int q   = lane >> 4;             // which tap of the 4 in this K-step
    const char* fb = (const char*)ft;
    int offs[7];
    #pragma unroll
    for (int stp = 0; stp < 7; ++stp){
        int tap = 4*stp + q;
        if (tap >= 27) tap = 0;       // pad tap: safe addr, A is zero there
        offs[stp] = offb16(tap);
    }
    for (int yy = 0; yy < 2; ++yy){
        int yl = (w >> 1)*2 + yy;
        int rowb = ((cl*6 + yl)*66 + col)*16;
        #pragma unroll
        for (int xp = 0; xp < 2; ++xp){
            int b0off = rowb + xp*512;        // 32 px * 16 B
            int b1off = b0off + 256;          // +16 px
            floatx4 acc0 = {0.f,0.f,0.f,0.f};
            floatx4 acc1 = {0.f,0.f,0.f,0.f};
            #pragma unroll
            for (int stp = 0; stp < 7; ++stp){
                short8 b0 = *(const short8*)(fb + b0off + offs[stp]);
                short8 b1 = *(const short8*)(fb + b1off + offs[stp]);
                acc0 = __builtin_amdgcn_mfma_f32_16x16x32_bf16(afr[stp], b0, acc0, 0, 0, 0);
                acc1 = __builtin_amdgcn_mfma_f32_16x16x32_bf16(afr[stp], b1, acc1, 0, 0, 0);
            }
            // C/D: col = lane&15, row = (lane>>4)*4 + reg; rows 8..15 pad
            if (lane < 32){
                int y = y0 + yl;
                int xa = xp*32 + col;
                #pragma unroll
                for (int rg = 0; rg < 4; ++rg){
                    int o = (lane >> 4)*4 + rg;
                    size_t ob = (((size_t)(n*TT + o))*CC + c_out)*HW + y*WW;
                    out[ob + xa]      = acc0[rg];
                    out[ob + xa + 16] = acc1[rg];
                }
            }
        }
    }
}

// ---------------- K5 fallback (tiny ws): masked on-the-fly version --------
__global__ __launch_bounds__(256) void k5_conv3d(
        const float* __restrict__ x,
        const float* __restrict__ impf, const float* __restrict__ wlast,
        const float* __restrict__ maps, float* __restrict__ out){
    __shared__ __align__(16) u16 fim[1584*8];
    __shared__ __align__(16) u16 fsb[1584*8];
    __shared__ u32 maskw[CC*4];
    int tid  = threadIdx.x;
    int lane = tid & 63;
    int w    = tid >> 6;
    int c0 = blockIdx.x * 2;
    int y0 = blockIdx.y * 4;
    int n  = blockIdx.z;

    for (int idx = tid; idx < CC*4; idx += 256){
        int c = idx >> 2, j = idx & 3;
        u32 m = (impf[(2*j)*CC + c]   > 0.f ? 0x0000FFFFu : 0u)
              | (impf[(2*j+1)*CC + c] > 0.f ? 0xFFFF0000u : 0u);
        maskw[idx] = m;
    }

    for (int idx = tid; idx < 896; idx += 256){
        int stp = idx >> 6;
        int l   = idx & 63;
        int m = l & 15, q = l >> 4;
        int i0 = (q & 1) * 8, s = q >> 1;
        int tap = 2*stp + s;
        bool valid = (m < 8) && (tap < 27);
        union { u16 h[8]; uint4 v; } pk;
        #pragma unroll
        for (int j = 0; j < 8; ++j){
            float wv = valid ? wlast[(m*16 + i0 + j)*27 + tap] : 0.f;
            pk.h[j] = f2bf(wv);
        }
        *(uint4*)(fim + idx*8) = pk.v;
    }
    __syncthreads();
    short8 afr[14];
    #pragma unroll
    for (int stp = 0; stp < 14; ++stp)
        afr[stp] = *(const short8*)(fim + (stp*64 + lane)*8);
    __syncthreads();

    for (int idx = tid; idx < 1584; idx += 256){
        int cc  = idx / 396;
        int rm  = idx % 396;
        int yyl = rm / 66;
        int xx  = rm % 66;
        int gc = c0 - 1 + cc;
        int gy = y0 - 1 + yyl;
        int gx = xx - 1;
        uint4 vim = make_uint4(0,0,0,0), vsb = make_uint4(0,0,0,0);
        if ((u32)gc < CC && (u32)gy < HH && (u32)gx < WW){
            int gp = gy*WW + gx;
            u32 al[4];
            const float* xn  = x    + ((size_t)(n*TT)*CC + gc)*HW + gp;
            const float* mpn = maps + ((size_t)n*TT*2)*HW + gp;
            u16 hv[8];
            #pragma unroll
            for (int t = 0; t < TT; ++t){
                float ip = impf[t*CC + gc];
                float xv = xn[(size_t)t*CC*HW];
                float mv = mpn[((size_t)t*2 + (ip > 0.f ? 0 : 1))*HW];
                hv[t] = f2bf(xv * mv);
            }
            #pragma unroll
            for (int j = 0; j < 4; ++j)
                al[j] = (u32)hv[2*j] | ((u32)hv[2*j+1] << 16);
            u32 m0 = maskw[gc*4+0], m1 = maskw[gc*4+1];
            u32 m2 = maskw[gc*4+2], m3 = maskw[gc*4+3];
            vim.x = al[0] & m0; vim.y = al[1] & m1;
            vim.z = al[2] & m2; vim.w = al[3] & m3;
            vsb.x = al[0] ^ vim.x; vsb.y = al[1] ^ vim.y;
            vsb.z = al[2] ^ vim.z; vsb.w = al[3] ^ vim.w;
        }
        *(uint4*)(fim + idx*8) = vim;
        *(uint4*)(fsb + idx*8) = vsb;
    }
    __syncthreads();

    int col = lane & 15;
    int q   = (lane >> 4) & 1;
    int s   = lane >> 5;
    const char* fb = (const char*)(q ? fsb : fim);
    int offs[14];
    #pragma unroll
    for (int stp = 0; stp < 14; ++stp){
        int tap = 2*stp + s;
        if (tap >= 27) tap = 0;
        offs[stp] = offb16(tap);
    }
    int cl = w & 1;
    for (int yy = 0; yy < 2; ++yy){
        int yl = (w >> 1)*2 + yy;
        int rowb = ((cl*6 + yl)*66 + col)*16;
        #pragma unroll
        for (int xp = 0; xp < 2; ++xp){
            int b0off = rowb + xp*512;
            int b1off = b0off + 256;
            floatx4 acc0 = {0.f,0.f,0.f,0.f};
            floatx4 acc1 = {0.f,0.f,0.f,0.f};
            #pragma unroll
            for (int stp = 0; stp < 14; ++stp){
                short8 b0 = *(const short8*)(fb + b0off + offs[stp]);
                short8 b1 = *(const short8*)(fb + b1off + offs[stp]);
                acc0 = __builtin_amdgcn_mfma_f32_16x16x32_bf16(afr[stp], b0, acc0, 0, 0, 0);
                acc1 = __builtin_amdgcn_mfma_f32_16x16x32_bf16(afr[stp], b1, acc1, 0, 0, 0);
            }
            if (lane < 32){
                int c = c0 + cl, y = y0 + yl;
                int xa = xp*32 + col;
                #pragma unroll
                for (int rg = 0; rg < 4; ++rg){
                    int o = (lane >> 4)*4 + rg;
                    size_t ob = (((size_t)(n*TT + o))*CC + c)*HW + y*WW;
                    out[ob + xa]      = acc0[rg];
                    out[ob + xa + 16] = acc1[rg];
                }
            }
        }
    }
}

extern "C" void kernel_launch(void* const* d_in, const int* in_sizes, int n_in,
                              void* d_out, int out_size, void* d_ws, size_t ws_size,
                              hipStream_t stream){
    const float* x     = (const float*)d_in[0];   // (8,8,128,64,64) fp32
    const float* w1    = (const float*)d_in[1];   // (1,2,3,3)
    const float* w2    = (const float*)d_in[2];   // (1,2,3,3)
    const float* wlast = (const float*)d_in[3];   // (8,16,3,3,3)
    float* out = (float*)d_out;

    float* ws   = (float*)d_ws;
    float* M    = ws;                           // 8,192 f32
    float* imp  = ws + 8192;                    // 1,024 f32
    float* maps = ws + 9216;                    // 524,288 f32
    u16*   st   = (u16*)(ws + 9216 + 524288);   // 1,048,576 u16 (2 MB)
    u16*   fw   = st;   // folded A-fragments (917,504 B) alias st (dead after k3b)
    const size_t WS_MAIN = (size_t)(9216 + 524288 + 524288) * 4;   // ~4.2 MB

    k1_M      <<<dim3(NN*TT*CC/4), dim3(256), 0, stream>>>(x, M);
    k2_imp    <<<dim3(TT),         dim3(128), 0, stream>>>(M, imp);
    k3a_stats <<<dim3(NN*TT, 2),   dim3(512), 0, stream>>>(x, imp, st);
    k3b_maps  <<<dim3(NN*TT, 4),   dim3(256), 0, stream>>>(st, w1, w2, maps);
    if (ws_size >= WS_MAIN){
        kW_frag <<<dim3(CC, 7), dim3(64), 0, stream>>>(wlast, imp, fw);
        k5_fuse <<<dim3(CC/2, HH/4, NN), dim3(256), 0, stream>>>(x, imp, maps, fw, out);
    } else {
        k5_conv3d <<<dim3(CC/2, HH/4, NN), dim3(256), 0, stream>>>(x, imp, wlast, maps, out);
    }
}